// Round 1
// baseline (314.105 us; speedup 1.0000x reference)
//
#include <hip/hip_runtime.h>

#define B_  8
#define N_  16384
#define NC_ 64
#define C_  256

typedef __attribute__((ext_vector_type(8))) short bf16x8;
typedef __attribute__((ext_vector_type(4))) float f32x4;

// ws layout:
//   [0, 262144)                  : WpT (W_p transposed, fp32 256x256)
//   [262144, 262144+8*98304)     : per-batch blob b: {Vhi 32KB | Vlo 32KB | CfT 32KB}, bf16, pre-swizzled
//   [+8*98304, +2048)            : s0, fp32 B*64
#define WS_BLOB_OFF 262144
#define WS_S0_OFF   (262144 + 8*98304)

__device__ __forceinline__ unsigned rne_bf16(float f) {
    unsigned u = __float_as_uint(f);
    return (u + 0x7fffu + ((u >> 16) & 1u)) >> 16;   // round-to-nearest-even bf16 bits
}

__device__ __forceinline__ f32x4 mfma16(bf16x8 a, bf16x8 b, f32x4 c) {
    // D[r][c] = sum_k A[r][k]*B[c][k]; C-layout: col=lane&15, row=(lane>>4)*4+reg
    return __builtin_amdgcn_mfma_f32_16x16x32_bf16(a, b, c, 0, 0, 0);
}

// ---------------- kernel A0: transpose W_p (256x256 fp32) ----------------
__global__ __launch_bounds__(256) void k_transpose(const float* __restrict__ A,
                                                   float* __restrict__ At) {
    __shared__ float t[16][17];
    int bi = blockIdx.x >> 4, bj = blockIdx.x & 15;
    int tx = threadIdx.x & 15, ty = threadIdx.x >> 4;
    t[ty][tx] = A[(bi*16 + ty)*C_ + bj*16 + tx];
    __syncthreads();
    At[(bj*16 + ty)*C_ + bi*16 + tx] = t[tx][ty];
}

// ---------------- kernel A1: per-batch precompute ----------------
// block = (b, kgroup of 8 centroids); computes c_proj rows, then Vt (hi/lo bf16,
// swizzled), CfT (bf16, swizzled), s0.
__global__ __launch_bounds__(256) void k_pre(const float* __restrict__ Cf,
        const float* __restrict__ Wc, const float* __restrict__ bc,
        const float* __restrict__ bp, const float* __restrict__ WpT,
        char* __restrict__ blob, float* __restrict__ s0g) {
    int b  = blockIdx.x >> 3;
    int kg = blockIdx.x & 7;
    int t  = threadIdx.x;           // 0..255
    __shared__ float cfL[8][256];
    __shared__ float vL[8][256];

    const float* cfb = Cf + ((size_t)b*NC_ + kg*8) * C_;
    #pragma unroll
    for (int kk = 0; kk < 8; ++kk) cfL[kk][t] = cfb[kk*C_ + t];
    __syncthreads();

    // c_proj: v[kk][d] for d = t
    float acc[8];
    float bcv = bc[t];
    #pragma unroll
    for (int kk = 0; kk < 8; ++kk) acc[kk] = bcv;
    #pragma unroll 4
    for (int c = 0; c < C_; ++c) {
        float wv = Wc[c*C_ + t];
        #pragma unroll
        for (int kk = 0; kk < 8; ++kk) acc[kk] = fmaf(cfL[kk][c], wv, acc[kk]);
    }
    #pragma unroll
    for (int kk = 0; kk < 8; ++kk) vL[kk][t] = acc[kk];
    __syncthreads();

    // s0[k] = bp . v[k]   (wave 0)
    if (t < 64) {
        #pragma unroll
        for (int kk = 0; kk < 8; ++kk) {
            float s = 0.f;
            #pragma unroll
            for (int j = 0; j < 4; ++j) { int d = t + j*64; s += bp[d]*vL[kk][d]; }
            #pragma unroll
            for (int m = 32; m >= 1; m >>= 1) s += __shfl_xor(s, m);
            if (t == 0) s0g[b*NC_ + kg*8 + kk] = s;
        }
    }

    // Vt[k][c] = sum_d Wp[c][d]*v[k][d]   (c = t, coalesced via WpT)
    float vt[8];
    #pragma unroll
    for (int kk = 0; kk < 8; ++kk) vt[kk] = 0.f;
    #pragma unroll 4
    for (int d = 0; d < C_; ++d) {
        float wv = WpT[d*C_ + t];
        #pragma unroll
        for (int kk = 0; kk < 8; ++kk) vt[kk] = fmaf(wv, vL[kk][d], vt[kk]);
    }

    char* vhiB = blob + (size_t)b*98304;
    char* vloB = vhiB + 32768;
    char* cftB = vhiB + 65536;
    #pragma unroll
    for (int kk = 0; kk < 8; ++kk) {
        int row = kg*8 + kk;                         // centroid index 0..63
        unsigned hb = rne_bf16(vt[kk]);
        float hf = __uint_as_float(hb << 16);
        unsigned lb = rne_bf16(vt[kk] - hf);
        // Vhi/Vlo: [row][c] bf16, row stride 512B, swizzle ^((row&15)<<4)
        unsigned off = ((unsigned)(row*512 + t*2)) ^ ((unsigned)(row & 15) << 4);
        *(unsigned short*)(vhiB + off) = (unsigned short)hb;
        *(unsigned short*)(vloB + off) = (unsigned short)lb;
        // CfT: [c][k] bf16, row stride 128B, swizzle ^((c&7)<<4)
        unsigned offc = ((unsigned)(t*128 + row*2)) ^ ((unsigned)(t & 7) << 4);
        *(unsigned short*)(cftB + offc) = (unsigned short)rne_bf16(cfL[kk][t]);
    }
}

// ---------------- main kernel ----------------
// block: 512 thr = 8 waves, 128 point-rows (16/wave). LDS 112.25KB -> 1 block/CU.
__global__ __launch_bounds__(512, 2) void k_main(const float* __restrict__ P,
        const char* __restrict__ blob, const float* __restrict__ s0g,
        float* __restrict__ out) {
    __shared__ __align__(16) char smem[114944];
    // smem: [0,32768) Vhi | [32768,65536) Vlo | [65536,98304) CfT | [98304,98560) s0 | [98560,..) Wbuf 8*2KB
    float* s0L   = (float*)(smem + 98304);
    char*  wbAll = smem + 98560;

    const int nb = N_ / 128;
    int b    = blockIdx.x / nb;
    int tile = blockIdx.x % nb;
    int row_blk = tile * 128;
    int tid = threadIdx.x;
    int w   = tid >> 6;
    int l   = tid & 63;
    int l15 = l & 15;
    int g   = l >> 4;

    // ---- stage per-batch constants (already swizzled in global) ----
    {
        const f32x4* src = (const f32x4*)(blob + (size_t)b*98304);
        f32x4* dst = (f32x4*)smem;
        #pragma unroll 4
        for (int i = tid; i < 6144; i += 512) dst[i] = src[i];
        if (tid < 64) s0L[tid] = s0g[b*NC_ + tid];
    }
    __syncthreads();

    // ---- prefetch this wave's 16 P-rows as A-fragments (fp32 in regs) ----
    int prow = row_blk + w*16 + l15;
    const float* Prow = P + ((size_t)b*N_ + prow)*C_ + g*8;
    f32x4 pf[16];
    #pragma unroll
    for (int kk = 0; kk < 8; ++kk) {
        pf[2*kk]   = *(const f32x4*)(Prow + kk*32);
        pf[2*kk+1] = *(const f32x4*)(Prow + kk*32 + 4);
    }

    // ---- scores: S^T(64 x 16) = Vt * P^T, acc seeded with s0 ----
    f32x4 sacc[4];
    #pragma unroll
    for (int mf = 0; mf < 4; ++mf) {
        #pragma unroll
        for (int r = 0; r < 4; ++r) sacc[mf][r] = s0L[mf*16 + g*4 + r];
    }

    #pragma unroll
    for (int kk = 0; kk < 8; ++kk) {
        bf16x8 phi, plo;
        #pragma unroll
        for (int h = 0; h < 2; ++h) {
            #pragma unroll
            for (int j = 0; j < 4; ++j) {
                float f  = pf[2*kk + h][j];
                unsigned hb = rne_bf16(f);
                float hf = __uint_as_float(hb << 16);
                unsigned lb = rne_bf16(f - hf);
                phi[h*4 + j] = (short)hb;
                plo[h*4 + j] = (short)lb;
            }
        }
        #pragma unroll
        for (int mf = 0; mf < 4; ++mf) {
            unsigned off = ((unsigned)((mf*16 + l15)*512 + kk*64 + g*16)) ^ ((unsigned)l15 << 4);
            bf16x8 vh = *(const bf16x8*)(smem + off);
            bf16x8 vl = *(const bf16x8*)(smem + 32768 + off);
            sacc[mf] = mfma16(vh, phi, sacc[mf]);   // Phi*Vhi
            sacc[mf] = mfma16(vh, plo, sacc[mf]);   // Plo*Vhi
            sacc[mf] = mfma16(vl, phi, sacc[mf]);   // Phi*Vlo
        }
    }

    // ---- softmax over the 64 centroids (lane holds 16, partners at ^16,^32) ----
    float mx = -3.0e38f;
    #pragma unroll
    for (int mf = 0; mf < 4; ++mf)
        #pragma unroll
        for (int r = 0; r < 4; ++r) mx = fmaxf(mx, sacc[mf][r]);
    mx = fmaxf(mx, __shfl_xor(mx, 16));
    mx = fmaxf(mx, __shfl_xor(mx, 32));
    float sum = 0.f;
    float pv[4][4];
    #pragma unroll
    for (int mf = 0; mf < 4; ++mf)
        #pragma unroll
        for (int r = 0; r < 4; ++r) {
            float e = __expf(sacc[mf][r] - mx);
            pv[mf][r] = e; sum += e;
        }
    sum += __shfl_xor(sum, 16);
    sum += __shfl_xor(sum, 32);
    float inv = 1.0f / sum;

    // ---- round-trip weights through per-wave swizzled LDS into A-frag layout ----
    char* wb = wbAll + w*2048;   // [pointrow 16][k 64] bf16, swz ^((row&7)<<4)
    #pragma unroll
    for (int mf = 0; mf < 4; ++mf) {
        unsigned w01 = rne_bf16(pv[mf][0]*inv) | (rne_bf16(pv[mf][1]*inv) << 16);
        unsigned w23 = rne_bf16(pv[mf][2]*inv) | (rne_bf16(pv[mf][3]*inv) << 16);
        unsigned off = ((unsigned)(l15*128 + mf*32 + g*8)) ^ ((unsigned)(l15 & 7) << 4);
        uint2 v; v.x = w01; v.y = w23;
        *(uint2*)(wb + off) = v;
    }

    // ---- PV: O(16 x 256) = W * Cf ----
    f32x4 zero = {0.f, 0.f, 0.f, 0.f};
    f32x4 oacc[16];
    #pragma unroll
    for (int nf = 0; nf < 16; ++nf) oacc[nf] = zero;
    #pragma unroll
    for (int kk2 = 0; kk2 < 2; ++kk2) {
        unsigned woff = ((unsigned)(l15*128 + kk2*64 + g*16)) ^ ((unsigned)(l15 & 7) << 4);
        bf16x8 wf = *(const bf16x8*)(wb + woff);
        #pragma unroll
        for (int nf = 0; nf < 16; ++nf) {
            unsigned coff = ((unsigned)((nf*16 + l15)*128 + kk2*64 + g*16)) ^ ((unsigned)(l15 & 7) << 4);
            bf16x8 cf = *(const bf16x8*)(smem + 65536 + coff);
            oacc[nf] = mfma16(wf, cf, oacc[nf]);
        }
    }

    // ---- epilogue: out = P + O (P re-read, L2-hot) ----
    size_t obase = ((size_t)b*N_ + row_blk + w*16 + g*4) * C_;
    #pragma unroll
    for (int nf = 0; nf < 16; ++nf) {
        #pragma unroll
        for (int r = 0; r < 4; ++r) {
            size_t idx = obase + (size_t)r*C_ + nf*16 + l15;
            out[idx] = P[idx] + oacc[nf][r];
        }
    }
}

extern "C" void kernel_launch(void* const* d_in, const int* in_sizes, int n_in,
                              void* d_out, int out_size, void* d_ws, size_t ws_size,
                              hipStream_t stream) {
    const float* P  = (const float*)d_in[0];
    const float* Cf = (const float*)d_in[1];
    const float* Wp = (const float*)d_in[2];
    const float* bp = (const float*)d_in[3];
    const float* Wc = (const float*)d_in[4];
    const float* bc = (const float*)d_in[5];
    float* out = (float*)d_out;

    float* WpT = (float*)d_ws;
    char*  blob = (char*)d_ws + WS_BLOB_OFF;
    float* s0   = (float*)((char*)d_ws + WS_S0_OFF);

    k_transpose<<<256, 256, 0, stream>>>(Wp, WpT);
    k_pre<<<64, 256, 0, stream>>>(Cf, Wc, bc, bp, WpT, blob, s0);
    k_main<<<B_*(N_/128), 512, 0, stream>>>(P, blob, s0, out);
}

// Round 2
// 290.227 us; speedup vs baseline: 1.0823x; 1.0823x over previous
//
#include <hip/hip_runtime.h>

#define B_  8
#define N_  16384
#define NC_ 64
#define C_  256

typedef __attribute__((ext_vector_type(8))) short bf16x8;
typedef __attribute__((ext_vector_type(4))) float f32x4;

// ws layout (bytes):
#define WS_GT   0           // GT[c][e] = G[e][c] = sum_d Wc[e,d]*Wp[c,d], 256x256 f32
#define WS_BLOB 262144      // per batch: Vhi 32KB | CfT 32KB (x8 batches = 512KB)
#define WS_S0   786432      // B*64 f32
#define WS_WFB  788480      // 256 f32  (Wc . bp)
#define WS_H    789504      // 256 f32  (bc . Wp[c,:])
#define WS_BB   790528      // 1 f32    (bc . bp)

__device__ __forceinline__ unsigned rne_bf16(float f) {
    unsigned u = __float_as_uint(f);
    return (u + 0x7fffu + ((u >> 16) & 1u)) >> 16;   // round-to-nearest-even bf16 bits
}

__device__ __forceinline__ f32x4 mfma16(bf16x8 a, bf16x8 b, f32x4 c) {
    // D[r][c] = sum_k A[r][k]*B[c][k]; C/D: col=lane&15, row=(lane>>4)*4+reg
    return __builtin_amdgcn_mfma_f32_16x16x32_bf16(a, b, c, 0, 0, 0);
}

// ---------------- P1: G = Wc*Wp^T (stored transposed), h, wfb, bb ----------------
// grid 256 (one output column c of G), block 256.
__global__ __launch_bounds__(256) void k_p1(const float* __restrict__ Wp,
        const float* __restrict__ Wc, const float* __restrict__ bc,
        const float* __restrict__ bp, float* __restrict__ ws) {
    __shared__ float WpL[256];
    __shared__ float bpL[256];
    __shared__ float red[4];
    int c = blockIdx.x, t = threadIdx.x;
    WpL[t] = Wp[(size_t)c*C_ + t];      // Wp row c
    bpL[t] = bp[t];
    float bcv = bc[t];
    __syncthreads();

    // G[e=t][c] = sum_d Wc[t][d] * Wp[c][d]  -> GT[c][t]
    const float* wcr = Wc + (size_t)t*C_;
    float acc = 0.f;
    #pragma unroll 8
    for (int d = 0; d < C_; d += 4) {
        f32x4 wv = *(const f32x4*)(wcr + d);
        f32x4 wp = *(const f32x4*)(WpL + d);
        acc += wv[0]*wp[0] + wv[1]*wp[1] + wv[2]*wp[2] + wv[3]*wp[3];
    }
    ws[WS_GT/4 + c*C_ + t] = acc;

    // h[c] = sum_d bc[d]*Wp[c][d]
    float hp = bcv * WpL[t];
    #pragma unroll
    for (int m = 32; m; m >>= 1) hp += __shfl_xor(hp, m);
    if ((t & 63) == 0) red[t >> 6] = hp;
    __syncthreads();
    if (t == 0) ws[WS_H/4 + c] = red[0] + red[1] + red[2] + red[3];

    if (c == 0) {
        // wfb[e=t] = sum_d Wc[t][d]*bp[d]
        float aw = 0.f;
        #pragma unroll 8
        for (int d = 0; d < C_; d += 4) {
            f32x4 wv = *(const f32x4*)(wcr + d);
            f32x4 b4 = *(const f32x4*)(bpL + d);
            aw += wv[0]*b4[0] + wv[1]*b4[1] + wv[2]*b4[2] + wv[3]*b4[3];
        }
        ws[WS_WFB/4 + t] = aw;
        // bb = bc . bp
        float pb = bcv * bpL[t];
        #pragma unroll
        for (int m = 32; m; m >>= 1) pb += __shfl_xor(pb, m);
        __syncthreads();                      // protect red[] (h-read done)
        if ((t & 63) == 0) red[t >> 6] = pb;
        __syncthreads();
        if (t == 0) ws[WS_BB/4] = red[0] + red[1] + red[2] + red[3];
    }
}

// ---------------- P2: per-batch Vt = Cf*G + h (bf16, swizzled), CfT, s0 ----------------
// grid 64 = (b, kgroup of 8 centroids), block 256.
__global__ __launch_bounds__(256) void k_p2(const float* __restrict__ Cf,
        float* __restrict__ ws) {
    __shared__ float CfL[8][256];
    __shared__ float wfbL[256];
    int b = blockIdx.x >> 3, kg = blockIdx.x & 7;
    int t = threadIdx.x;
    const float* cfb = Cf + ((size_t)b*NC_ + kg*8)*C_;
    #pragma unroll
    for (int kk = 0; kk < 8; ++kk) CfL[kk][t] = cfb[kk*C_ + t];
    wfbL[t] = ws[WS_WFB/4 + t];
    float hv = ws[WS_H/4 + t];
    float bb = ws[WS_BB/4];
    __syncthreads();

    char* vhiB = (char*)ws + WS_BLOB + (size_t)b*65536;
    char* cftB = vhiB + 32768;

    // CfT bf16: [feature c][centroid k], row stride 128B, swz ^((c&7)<<4)
    #pragma unroll
    for (int kk = 0; kk < 8; ++kk) {
        unsigned offc = ((unsigned)(t*128 + (kg*8 + kk)*2)) ^ ((unsigned)(t & 7) << 4);
        *(unsigned short*)(cftB + offc) = (unsigned short)rne_bf16(CfL[kk][t]);
    }

    // Vt[k][c=t] = h[t] + sum_e CfL[k][e] * GT[t][e]
    float acc[8];
    #pragma unroll
    for (int kk = 0; kk < 8; ++kk) acc[kk] = hv;
    const float* gtr = ws + WS_GT/4 + (size_t)t*C_;
    #pragma unroll 4
    for (int e = 0; e < C_; e += 4) {
        f32x4 g4 = *(const f32x4*)(gtr + e);
        #pragma unroll
        for (int kk = 0; kk < 8; ++kk) {
            f32x4 c4 = *(const f32x4*)(&CfL[kk][e]);
            acc[kk] += g4[0]*c4[0] + g4[1]*c4[1] + g4[2]*c4[2] + g4[3]*c4[3];
        }
    }
    // Vhi: [centroid row][feature c], row stride 512B, swz ^((row&15)<<4)
    #pragma unroll
    for (int kk = 0; kk < 8; ++kk) {
        int row = kg*8 + kk;
        unsigned off = ((unsigned)(row*512 + t*2)) ^ ((unsigned)(row & 15) << 4);
        *(unsigned short*)(vhiB + off) = (unsigned short)rne_bf16(acc[kk]);
    }

    // s0[k] = Cf[k].wfb + bb   (wave w handles centroids 2w, 2w+1)
    int w = t >> 6, l = t & 63;
    #pragma unroll
    for (int kk = 2*w; kk < 2*w + 2; ++kk) {
        float s = 0.f;
        #pragma unroll
        for (int j = 0; j < 4; ++j) s += CfL[kk][l + 64*j] * wfbL[l + 64*j];
        #pragma unroll
        for (int m = 32; m; m >>= 1) s += __shfl_xor(s, m);
        if (l == 0) ws[WS_S0/4 + b*NC_ + kg*8 + kk] = s + bb;
    }
}

// ---------------- main kernel: 512 thr = 8 waves, 128 rows/block, 80KB LDS, 2 blk/CU ----------------
__global__ __launch_bounds__(512, 4) void k_main(const float* __restrict__ P,
        const char* __restrict__ blob, const float* __restrict__ s0g,
        float* __restrict__ out) {
    __shared__ __align__(16) char smem[81920];
    // [0,32768) Vhi | [32768,65536) CfT | [65536,81920) wb: 8 waves x 2KB
    char* wbAll = smem + 65536;

    const int nb = N_ / 128;
    int b    = blockIdx.x / nb;
    int tile = blockIdx.x % nb;
    int row_blk = tile * 128;
    int tid = threadIdx.x;
    int w   = tid >> 6;
    int l   = tid & 63;
    int l15 = l & 15;
    int g   = l >> 4;

    // ---- issue P loads early (16 x dwordx4, HBM) ----
    int prow = row_blk + w*16 + l15;
    const float* Prow = P + ((size_t)b*N_ + prow)*C_ + g*8;
    f32x4 pf[16];
    #pragma unroll
    for (int kk = 0; kk < 8; ++kk) {
        pf[2*kk]   = *(const f32x4*)(Prow + kk*32);
        pf[2*kk+1] = *(const f32x4*)(Prow + kk*32 + 4);
    }
    // ---- s0 seed (L2-hot vector loads) ----
    f32x4 sacc[4];
    #pragma unroll
    for (int mf = 0; mf < 4; ++mf)
        sacc[mf] = *(const f32x4*)(s0g + b*NC_ + mf*16 + g*4);

    // ---- stage per-batch constants (64KB, pre-swizzled, L2-hot) ----
    {
        const f32x4* src = (const f32x4*)(blob + (size_t)b*65536);
        f32x4* dst = (f32x4*)smem;
        #pragma unroll
        for (int i = 0; i < 8; ++i) dst[tid + i*512] = src[tid + i*512];
    }
    __syncthreads();

    // ---- scores: S^T(64x16) = Vt * P^T (P split hi+lo) ----
    #pragma unroll
    for (int kk = 0; kk < 8; ++kk) {
        bf16x8 phi, plo;
        #pragma unroll
        for (int h = 0; h < 2; ++h) {
            #pragma unroll
            for (int j = 0; j < 4; ++j) {
                float f  = pf[2*kk + h][j];
                unsigned hb = rne_bf16(f);
                float hf = __uint_as_float(hb << 16);
                unsigned lb = rne_bf16(f - hf);
                phi[h*4 + j] = (short)hb;
                plo[h*4 + j] = (short)lb;
            }
        }
        #pragma unroll
        for (int mf = 0; mf < 4; ++mf) {
            unsigned off = ((unsigned)((mf*16 + l15)*512 + kk*64 + g*16)) ^ ((unsigned)l15 << 4);
            bf16x8 vh = *(const bf16x8*)(smem + off);
            sacc[mf] = mfma16(vh, phi, sacc[mf]);
            sacc[mf] = mfma16(vh, plo, sacc[mf]);
        }
    }

    // ---- softmax over 64 centroids (lane holds 16; partners ^16, ^32) ----
    float mx = -3.0e38f;
    #pragma unroll
    for (int mf = 0; mf < 4; ++mf)
        #pragma unroll
        for (int r = 0; r < 4; ++r) mx = fmaxf(mx, sacc[mf][r]);
    mx = fmaxf(mx, __shfl_xor(mx, 16));
    mx = fmaxf(mx, __shfl_xor(mx, 32));
    float sum = 0.f;
    float pv[4][4];
    #pragma unroll
    for (int mf = 0; mf < 4; ++mf)
        #pragma unroll
        for (int r = 0; r < 4; ++r) {
            float e = __expf(sacc[mf][r] - mx);
            pv[mf][r] = e; sum += e;
        }
    sum += __shfl_xor(sum, 16);
    sum += __shfl_xor(sum, 32);
    float inv = 1.0f / sum;

    // ---- weights -> per-wave swizzled LDS -> A-frag layout ----
    char* wb = wbAll + w*2048;   // [pointrow 16][k 64] bf16, swz ^((row&7)<<4)
    #pragma unroll
    for (int mf = 0; mf < 4; ++mf) {
        unsigned w01 = rne_bf16(pv[mf][0]*inv) | (rne_bf16(pv[mf][1]*inv) << 16);
        unsigned w23 = rne_bf16(pv[mf][2]*inv) | (rne_bf16(pv[mf][3]*inv) << 16);
        unsigned off = ((unsigned)(l15*128 + mf*32 + g*8)) ^ ((unsigned)(l15 & 7) << 4);
        uint2 v; v.x = w01; v.y = w23;
        *(uint2*)(wb + off) = v;
    }

    // ---- PV: O = W * Cf, computed as D[feature][point] for vectorized epilogue ----
    f32x4 zero = {0.f, 0.f, 0.f, 0.f};
    f32x4 oacc[16];
    #pragma unroll
    for (int nf = 0; nf < 16; ++nf) oacc[nf] = zero;
    #pragma unroll
    for (int kk2 = 0; kk2 < 2; ++kk2) {
        unsigned woff = ((unsigned)(l15*128 + kk2*64 + g*16)) ^ ((unsigned)(l15 & 7) << 4);
        bf16x8 wf = *(const bf16x8*)(wb + woff);
        #pragma unroll
        for (int nf = 0; nf < 16; ++nf) {
            unsigned coff = ((unsigned)((nf*16 + l15)*128 + kk2*64 + g*16)) ^ ((unsigned)(l15 & 7) << 4);
            bf16x8 cf = *(const bf16x8*)(smem + 32768 + coff);
            oacc[nf] = mfma16(cf, wf, oacc[nf]);   // A=CfT rows (features), B=weights (points)
        }
    }

    // ---- epilogue: out = P + O, vectorized f32x4 (lane owns point l15, 4 consecutive feats) ----
    size_t rowbase = ((size_t)b*N_ + row_blk + w*16 + l15) * C_;
    #pragma unroll
    for (int nf = 0; nf < 16; ++nf) {
        size_t idx = rowbase + nf*16 + g*4;
        f32x4 pr = *(const f32x4*)(P + idx);
        f32x4 o  = oacc[nf];
        f32x4 res = {pr[0]+o[0], pr[1]+o[1], pr[2]+o[2], pr[3]+o[3]};
        *(f32x4*)(out + idx) = res;
    }
}

extern "C" void kernel_launch(void* const* d_in, const int* in_sizes, int n_in,
                              void* d_out, int out_size, void* d_ws, size_t ws_size,
                              hipStream_t stream) {
    const float* P  = (const float*)d_in[0];
    const float* Cf = (const float*)d_in[1];
    const float* Wp = (const float*)d_in[2];
    const float* bp = (const float*)d_in[3];
    const float* Wc = (const float*)d_in[4];
    const float* bc = (const float*)d_in[5];
    float* out = (float*)d_out;
    float* ws  = (float*)d_ws;

    k_p1<<<256, 256, 0, stream>>>(Wp, Wc, bc, bp, ws);
    k_p2<<<64, 256, 0, stream>>>(Cf, ws);
    k_main<<<B_*(N_/128), 512, 0, stream>>>(P, (const char*)d_ws + WS_BLOB,
                                            ws + WS_S0/4, out);
}